// Round 6
// baseline (277.809 us; speedup 1.0000x reference)
//
#include <hip/hip_runtime.h>
#include <math.h>

// B=1, C=256, N=16^3=4096 tokens, 16 groups, 4 heads, d=64.
// Single persistent kernel: 256 blocks x 256 threads, grid barriers via
// device-scope atomics (poison-proof: phase values 1..3, 0xAA... reads negative).
#define N_TOK 4096
#define C_CH  256

typedef short bf16x8 __attribute__((ext_vector_type(8)));
typedef float f32x4  __attribute__((ext_vector_type(4)));
typedef unsigned short u16;

__device__ __forceinline__ u16 f2bf(float f) {
    union { float f; unsigned u; } v; v.f = f;
    unsigned r = v.u + 0x7FFF + ((v.u >> 16) & 1);   // RNE
    return (u16)(r >> 16);
}
// pack two floats to bf16 pair (truncation) in one v_perm_b32
__device__ __forceinline__ unsigned packtr(float a, float b) {
    union { float f; unsigned u; } ua, ub; ua.f = a; ub.f = b;
    return __builtin_amdgcn_perm(ub.u, ua.u, 0x07060302u);  // lo=hi16(a), hi=hi16(b)
}

// Grid barrier: block publishes monotone phase; poison 0xAAAAAAAA is negative as int,
// so it never satisfies `>= phase`; race-ahead (phase+1) still releases waiters.
__device__ __forceinline__ void gridbar(unsigned* slots, unsigned phase) {
    __threadfence();
    __syncthreads();
    if (threadIdx.x == 0)
        __hip_atomic_store(&slots[blockIdx.x], phase, __ATOMIC_RELEASE, __HIP_MEMORY_SCOPE_AGENT);
    if (threadIdx.x < 64) {
#pragma unroll 1
        for (int j = 0; j < 4; ++j) {
            while ((int)__hip_atomic_load(&slots[threadIdx.x * 4 + j],
                                          __ATOMIC_ACQUIRE, __HIP_MEMORY_SCOPE_AGENT) < (int)phase) {
                __builtin_amdgcn_s_sleep(1);
            }
        }
    }
    __syncthreads();
    __threadfence();
}

union SM {
    struct { float rs[4], rss[4]; } p1;
    struct { float mu[16], rstd[16]; u16 xn[16][264]; } p2;   // +8 pad
    u16 ps[4][4096];                                          // attn per-wave P (swizzled)
    struct { float buf[2][64][65]; float lb[2][64]; } cb;     // attn combine (33.8KB max)
};

struct Frags { bf16x8 ak[4][2]; bf16x8 bv[2][4]; };

__global__ __launch_bounds__(256, 1) void fused_attn_block(
        const float* __restrict__ x,
        const float* __restrict__ gamma,
        const float* __restrict__ beta,
        const float* __restrict__ wqkv,
        const float* __restrict__ wproj,
        const float* __restrict__ bproj,
        unsigned* __restrict__ slots,
        float2* __restrict__ part,
        u16* __restrict__ wq, u16* __restrict__ wp,
        u16* __restrict__ QT, u16* __restrict__ KTm, u16* __restrict__ Vc,
        u16* __restrict__ hT,
        float* __restrict__ out) {
    __shared__ SM sm;
    const int bid  = blockIdx.x;      // 0..255
    const int tid  = threadIdx.x;     // 0..255
    const int wave = tid >> 6, lane = tid & 63;
    const int quad = lane >> 4, low = lane & 15;
    const int low7 = low & 7;

    // ================= P1: weight cvt + GN partial sums (1 channel / block) ====
    {
        int i4 = (bid * 256 + tid) * 4;
        if (i4 < 196608) {
            float4 v = *(const float4*)(wqkv + i4);
            // Q rows pre-scaled by 0.125*log2(e) so softmax uses exp2 directly
            float s = (((i4 >> 8) % 192) < 64) ? 0.18033688f : 1.0f;
            u16 r[4] = { f2bf(v.x * s), f2bf(v.y * s), f2bf(v.z * s), f2bf(v.w * s) };
            *(uint2*)(wq + i4) = *(uint2*)r;
        } else {
            int j = i4 - 196608;
            float4 v = *(const float4*)(wproj + j);
            u16 r[4] = { f2bf(v.x), f2bf(v.y), f2bf(v.z), f2bf(v.w) };
            *(uint2*)(wp + j) = *(uint2*)r;
        }
        // GN partials: block bid covers channel bid (4096 floats = 1024 float4)
        const float4* xp = (const float4*)x + bid * 1024;
        float s = 0.f, ss = 0.f;
#pragma unroll
        for (int k = 0; k < 4; ++k) {
            float4 v = xp[tid + k * 256];
            s  += v.x + v.y + v.z + v.w;
            ss += v.x * v.x + v.y * v.y + v.z * v.z + v.w * v.w;
        }
#pragma unroll
        for (int off = 1; off < 64; off <<= 1) {
            s  += __shfl_xor(s, off, 64);
            ss += __shfl_xor(ss, off, 64);
        }
        if (lane == 0) { sm.p1.rs[wave] = s; sm.p1.rss[wave] = ss; }
        __syncthreads();
        if (tid == 0)
            part[bid] = make_float2(sm.p1.rs[0] + sm.p1.rs[1] + sm.p1.rs[2] + sm.p1.rs[3],
                                    sm.p1.rss[0] + sm.p1.rss[1] + sm.p1.rss[2] + sm.p1.rss[3]);
    }
    gridbar(slots, 1);

    // ================= P2: stats finalize + normalize + QKV GEMM =================
    {
        if (tid < 16) {
            float s = 0.f, ss = 0.f;
#pragma unroll
            for (int j = 0; j < 16; ++j) { float2 p = part[tid * 16 + j]; s += p.x; ss += p.y; }
            float mu = s / 65536.f;
            float var = ss / 65536.f - mu * mu;
            sm.p2.mu[tid]   = mu;
            sm.p2.rstd[tid] = rsqrtf(var + 1e-5f);
        }
        __syncthreads();
        const int tok0 = bid * 16;
        {   // thread = channel c; 16 tokens
            const int c = tid;
            const float mu = sm.p2.mu[c >> 4], rs = sm.p2.rstd[c >> 4];
            const float g = gamma[c], bt = beta[c];
            const float4* xr = (const float4*)(x + c * N_TOK + tok0);
#pragma unroll
            for (int q4 = 0; q4 < 4; ++q4) {
                float4 v = xr[q4];
                sm.p2.xn[q4 * 4 + 0][c] = f2bf((v.x - mu) * rs * g + bt);
                sm.p2.xn[q4 * 4 + 1][c] = f2bf((v.y - mu) * rs * g + bt);
                sm.p2.xn[q4 * 4 + 2][c] = f2bf((v.z - mu) * rs * g + bt);
                sm.p2.xn[q4 * 4 + 3][c] = f2bf((v.w - mu) * rs * g + bt);
            }
        }
        __syncthreads();
        // wave = head; 12 m-tiles of 16 rows (0..3 Q, 4..7 K, 8..11 V)
        f32x4 acc[12];
#pragma unroll
        for (int mt = 0; mt < 12; ++mt) acc[mt] = f32x4{0, 0, 0, 0};
#pragma unroll
        for (int kc = 0; kc < 8; ++kc) {
            bf16x8 bfrag = *(const bf16x8*)(&sm.p2.xn[low][kc * 32 + quad * 8]);
#pragma unroll
            for (int mt = 0; mt < 12; ++mt) {
                bf16x8 afrag = *(const bf16x8*)(wq + (wave * 192 + mt * 16 + low) * 256 + kc * 32 + quad * 8);
                acc[mt] = __builtin_amdgcn_mfma_f32_16x16x32_bf16(afrag, bfrag, acc[mt], 0, 0, 0);
            }
        }
        const int tok = tok0 + low;
#pragma unroll
        for (int mt = 0; mt < 4; ++mt)
#pragma unroll
            for (int r = 0; r < 4; ++r)
                QT[(wave * N_TOK + tok) * 64 + mt * 16 + quad * 4 + r] = f2bf(acc[mt][r]);
#pragma unroll
        for (int mt = 0; mt < 4; ++mt)
#pragma unroll
            for (int r = 0; r < 4; ++r)
                KTm[(wave * N_TOK + tok) * 64 + mt * 16 + quad * 4 + r] = f2bf(acc[4 + mt][r]);
#pragma unroll
        for (int mt = 0; mt < 4; ++mt)
#pragma unroll
            for (int r = 0; r < 4; ++r)
                Vc[(wave * 64 + mt * 16 + quad * 4 + r) * N_TOK + tok] = f2bf(acc[8 + mt][r]);
    }
    gridbar(slots, 2);

    // ================= P3: attention (waves-over-keys, fixed-max exp2) =================
    {
        const int head = bid >> 6;
        const int qb   = (bid & 63) * 64;
        const u16* Qh = QT  + head * N_TOK * 64;
        const u16* Kh = KTm + head * N_TOK * 64;
        const u16* Vh = Vc  + head * 64 * N_TOK;
        u16* Pw = sm.ps[wave];

        bf16x8 ones;
#pragma unroll
        for (int i = 0; i < 8; ++i) ones[i] = (short)0x3F80;

        bf16x8 bq[4][2];
#pragma unroll
        for (int tn = 0; tn < 4; ++tn)
#pragma unroll
            for (int kh = 0; kh < 2; ++kh)
                bq[tn][kh] = *(const bf16x8*)(Qh + (qb + tn * 16 + low) * 64 + kh * 32 + quad * 8);

        f32x4 oa[4][4], lC[4];
#pragma unroll
        for (int tm = 0; tm < 4; ++tm) {
            lC[tm] = f32x4{0, 0, 0, 0};
#pragma unroll
            for (int cn = 0; cn < 4; ++cn) oa[tm][cn] = f32x4{0, 0, 0, 0};
        }

        auto load_frags = [&](Frags& F, int sbase) {
#pragma unroll
            for (int sq = 0; sq < 4; ++sq)
#pragma unroll
                for (int kh = 0; kh < 2; ++kh)
                    F.ak[sq][kh] = *(const bf16x8*)(Kh + (sbase + sq * 16 + low) * 64 + kh * 32 + quad * 8);
#pragma unroll
            for (int f = 0; f < 2; ++f)
#pragma unroll
                for (int cn = 0; cn < 4; ++cn)
                    F.bv[f][cn] = *(const bf16x8*)(Vh + (cn * 16 + low) * N_TOK + sbase + f * 32 + quad * 8);
        };

        auto compute_tile = [&](const Frags& F) {
            f32x4 sa[4][4];
#pragma unroll
            for (int sq = 0; sq < 4; ++sq)
#pragma unroll
                for (int tn = 0; tn < 4; ++tn) sa[sq][tn] = f32x4{0, 0, 0, 0};
#pragma unroll
            for (int kh = 0; kh < 2; ++kh)
#pragma unroll
                for (int sq = 0; sq < 4; ++sq)
#pragma unroll
                    for (int tn = 0; tn < 4; ++tn)
                        sa[sq][tn] = __builtin_amdgcn_mfma_f32_16x16x32_bf16(F.ak[sq][kh], bq[tn][kh], sa[sq][tn], 0, 0, 0);
#pragma unroll
            for (int sq = 0; sq < 4; ++sq)
#pragma unroll
                for (int tn = 0; tn < 4; ++tn) {
                    float p0 = __builtin_amdgcn_exp2f(sa[sq][tn][0]);
                    float p1 = __builtin_amdgcn_exp2f(sa[sq][tn][1]);
                    float p2 = __builtin_amdgcn_exp2f(sa[sq][tn][2]);
                    float p3 = __builtin_amdgcn_exp2f(sa[sq][tn][3]);
                    uint2 pk; pk.x = packtr(p0, p1); pk.y = packtr(p2, p3);
                    int u = (sq * 2 + (quad >> 1)) ^ low7;
                    *(uint2*)(Pw + (tn * 16 + low) * 64 + u * 8 + (quad & 1) * 4) = pk;
                }
            asm volatile("s_waitcnt lgkmcnt(0)" ::: "memory");  // wave-private round-trip
#pragma unroll
            for (int tm = 0; tm < 4; ++tm)
#pragma unroll
                for (int f = 0; f < 2; ++f) {
                    bf16x8 ap = *(const bf16x8*)(Pw + (tm * 16 + low) * 64 + (((f * 4 + quad) ^ low7) * 8));
                    lC[tm] = __builtin_amdgcn_mfma_f32_16x16x32_bf16(ap, ones, lC[tm], 0, 0, 0);
#pragma unroll
                    for (int cn = 0; cn < 4; ++cn)
                        oa[tm][cn] = __builtin_amdgcn_mfma_f32_16x16x32_bf16(ap, F.bv[f][cn], oa[tm][cn], 0, 0, 0);
                }
        };

        Frags Fa, Fb;
        load_frags(Fa, wave * 64);
#pragma unroll 1
        for (int i = 0; i < 16; i += 2) {
            load_frags(Fb, (wave + 4 * (i + 1)) * 64);
            compute_tile(Fa);
            if (i + 2 < 16) load_frags(Fa, (wave + 4 * (i + 2)) * 64);
            compute_tile(Fb);
        }

        // in-block combine across 4 waves
        __syncthreads();
        if ((wave & 1) == 0) {
            int bsel = wave >> 1;
#pragma unroll
            for (int tm = 0; tm < 4; ++tm)
#pragma unroll
                for (int r = 0; r < 4; ++r) {
                    int t = tm * 16 + quad * 4 + r;
                    if (low == 0) sm.cb.lb[bsel][t] = lC[tm][r];
#pragma unroll
                    for (int cn = 0; cn < 4; ++cn)
                        sm.cb.buf[bsel][t][cn * 16 + low] = oa[tm][cn][r];
                }
        }
        __syncthreads();
        if ((wave & 1) == 1) {
            int bsel = wave >> 1;
#pragma unroll
            for (int tm = 0; tm < 4; ++tm)
#pragma unroll
                for (int r = 0; r < 4; ++r) {
                    int t = tm * 16 + quad * 4 + r;
                    if (low == 0) sm.cb.lb[bsel][t] += lC[tm][r];
#pragma unroll
                    for (int cn = 0; cn < 4; ++cn)
                        sm.cb.buf[bsel][t][cn * 16 + low] += oa[tm][cn][r];
                }
        }
        __syncthreads();
        {
            int t = tid >> 2, c0 = (tid & 3) * 16;
            float li = 1.f / (sm.cb.lb[0][t] + sm.cb.lb[1][t]);
#pragma unroll
            for (int j = 0; j < 16; ++j) {
                int c = c0 + j;
                float o = (sm.cb.buf[0][t][c] + sm.cb.buf[1][t][c]) * li;
                hT[(qb + t) * C_CH + head * 64 + c] = f2bf(o);
            }
        }
    }
    gridbar(slots, 3);

    // ================= P4: proj GEMM + bias + residual =================
    {
        const int tok0 = bid * 16;
        f32x4 pacc[4];
#pragma unroll
        for (int mt = 0; mt < 4; ++mt) pacc[mt] = f32x4{0, 0, 0, 0};
#pragma unroll
        for (int kc = 0; kc < 8; ++kc) {
            bf16x8 bfrag = *(const bf16x8*)(hT + (tok0 + low) * C_CH + kc * 32 + quad * 8);
#pragma unroll
            for (int mt = 0; mt < 4; ++mt) {
                bf16x8 afrag = *(const bf16x8*)(wp + (wave * 64 + mt * 16 + low) * 256 + kc * 32 + quad * 8);
                pacc[mt] = __builtin_amdgcn_mfma_f32_16x16x32_bf16(afrag, bfrag, pacc[mt], 0, 0, 0);
            }
        }
        const int tok = tok0 + low;
#pragma unroll
        for (int mt = 0; mt < 4; ++mt)
#pragma unroll
            for (int r = 0; r < 4; ++r) {
                int o = wave * 64 + mt * 16 + quad * 4 + r;
                out[o * N_TOK + tok] = pacc[mt][r] + bproj[o] + x[o * N_TOK + tok];
            }
    }
}

extern "C" void kernel_launch(void* const* d_in, const int* in_sizes, int n_in,
                              void* d_out, int out_size, void* d_ws, size_t ws_size,
                              hipStream_t stream) {
    const float* x      = (const float*)d_in[0];
    const float* gamma  = (const float*)d_in[1];
    const float* beta   = (const float*)d_in[2];
    const float* w_qkv  = (const float*)d_in[3];
    const float* w_proj = (const float*)d_in[4];
    const float* b_proj = (const float*)d_in[5];
    float* out = (float*)d_out;

    char* base = (char*)d_ws;
    unsigned* slots = (unsigned*)base;                 // 1 KB (poisoned 0xAA each call — by design)
    float2*   part  = (float2*)(base + 1024);          // 2 KB
    u16*      wq    = (u16*)(base + 4096);             // 384 KB
    u16*      wp    = (u16*)(base + 397312);           // 128 KB
    u16*      QT    = (u16*)(base + 528384);           // 2 MB
    u16*      KTm   = (u16*)(base + 2625536);          // 2 MB
    u16*      Vc    = (u16*)(base + 4722688);          // 2 MB
    u16*      hT    = (u16*)(base + 6819840);          // 2 MB

    fused_attn_block<<<256, 256, 0, stream>>>(x, gamma, beta, w_qkv, w_proj, b_proj,
                                              slots, part, wq, wp, QT, KTm, Vc, hT, out);
}

// Round 7
// 243.037 us; speedup vs baseline: 1.1431x; 1.1431x over previous
//
#include <hip/hip_runtime.h>
#include <math.h>

// B=1, C=256, N=16^3=4096 tokens, 16 groups, 4 heads, d=64.
// Single persistent kernel: 256 blocks x 256 threads, grid barriers via
// device-scope atomics (poison-proof: phase values 1..3, 0xAA... reads negative).
// R7: barrier polls are RELAXED (acquire hoisted to one fence post-spin) to kill
// the per-poll buffer_inv storm that froze R6.
#define N_TOK 4096
#define C_CH  256

typedef short bf16x8 __attribute__((ext_vector_type(8)));
typedef float f32x4  __attribute__((ext_vector_type(4)));
typedef unsigned short u16;

__device__ __forceinline__ u16 f2bf(float f) {
    union { float f; unsigned u; } v; v.f = f;
    unsigned r = v.u + 0x7FFF + ((v.u >> 16) & 1);   // RNE
    return (u16)(r >> 16);
}
// pack two floats to bf16 pair (truncation) in one v_perm_b32
__device__ __forceinline__ unsigned packtr(float a, float b) {
    union { float f; unsigned u; } ua, ub; ua.f = a; ub.f = b;
    return __builtin_amdgcn_perm(ub.u, ua.u, 0x07060302u);  // lo=hi16(a), hi=hi16(b)
}

// Grid barrier: block publishes monotone phase; poison 0xAAAAAAAA is negative as int,
// so it never satisfies `>= phase`; race-ahead (phase+1) still releases waiters.
// Polls are RELAXED (no per-load cache invalidate); one fence after the spin
// provides acquire; fence before the publish provides release.
__device__ __forceinline__ void gridbar(unsigned* slots, unsigned phase) {
    __threadfence();                     // release: flush this block's writes
    __syncthreads();
    if (threadIdx.x == 0)
        __hip_atomic_store(&slots[blockIdx.x], phase, __ATOMIC_RELAXED, __HIP_MEMORY_SCOPE_AGENT);
    if (threadIdx.x < 64) {
#pragma unroll 1
        for (int j = 0; j < 4; ++j) {
            while ((int)__hip_atomic_load(&slots[threadIdx.x * 4 + j],
                                          __ATOMIC_RELAXED, __HIP_MEMORY_SCOPE_AGENT) < (int)phase) {
                __builtin_amdgcn_s_sleep(4);
            }
        }
    }
    __syncthreads();
    __threadfence();                     // acquire: invalidate stale L1/L2 once
}

union SM {
    struct { float rs[4], rss[4]; } p1;
    struct { float mu[16], rstd[16]; u16 xn[16][264]; } p2;   // +8 pad
    u16 ps[4][4096];                                          // attn per-wave P (swizzled)
    struct { float buf[2][64][65]; float lb[2][64]; } cb;     // attn combine (33.8KB max)
};

struct Frags { bf16x8 ak[4][2]; bf16x8 bv[2][4]; };

__global__ __launch_bounds__(256, 1) void fused_attn_block(
        const float* __restrict__ x,
        const float* __restrict__ gamma,
        const float* __restrict__ beta,
        const float* __restrict__ wqkv,
        const float* __restrict__ wproj,
        const float* __restrict__ bproj,
        unsigned* __restrict__ slots,
        float2* __restrict__ part,
        u16* __restrict__ wq, u16* __restrict__ wp,
        u16* __restrict__ QT, u16* __restrict__ KTm, u16* __restrict__ Vc,
        u16* __restrict__ hT,
        float* __restrict__ out) {
    __shared__ SM sm;
    const int bid  = blockIdx.x;      // 0..255
    const int tid  = threadIdx.x;     // 0..255
    const int wave = tid >> 6, lane = tid & 63;
    const int quad = lane >> 4, low = lane & 15;
    const int low7 = low & 7;

    // ================= P1: weight cvt + GN partial sums (1 channel / block) ====
    {
        int i4 = (bid * 256 + tid) * 4;
        if (i4 < 196608) {
            float4 v = *(const float4*)(wqkv + i4);
            // Q rows pre-scaled by 0.125*log2(e) so softmax uses exp2 directly
            float s = (((i4 >> 8) % 192) < 64) ? 0.18033688f : 1.0f;
            u16 r[4] = { f2bf(v.x * s), f2bf(v.y * s), f2bf(v.z * s), f2bf(v.w * s) };
            *(uint2*)(wq + i4) = *(uint2*)r;
        } else {
            int j = i4 - 196608;
            float4 v = *(const float4*)(wproj + j);
            u16 r[4] = { f2bf(v.x), f2bf(v.y), f2bf(v.z), f2bf(v.w) };
            *(uint2*)(wp + j) = *(uint2*)r;
        }
        // GN partials: block bid covers channel bid (4096 floats = 1024 float4)
        const float4* xp = (const float4*)x + bid * 1024;
        float s = 0.f, ss = 0.f;
#pragma unroll
        for (int k = 0; k < 4; ++k) {
            float4 v = xp[tid + k * 256];
            s  += v.x + v.y + v.z + v.w;
            ss += v.x * v.x + v.y * v.y + v.z * v.z + v.w * v.w;
        }
#pragma unroll
        for (int off = 1; off < 64; off <<= 1) {
            s  += __shfl_xor(s, off, 64);
            ss += __shfl_xor(ss, off, 64);
        }
        if (lane == 0) { sm.p1.rs[wave] = s; sm.p1.rss[wave] = ss; }
        __syncthreads();
        if (tid == 0)
            part[bid] = make_float2(sm.p1.rs[0] + sm.p1.rs[1] + sm.p1.rs[2] + sm.p1.rs[3],
                                    sm.p1.rss[0] + sm.p1.rss[1] + sm.p1.rss[2] + sm.p1.rss[3]);
    }
    gridbar(slots, 1);

    // ================= P2: stats finalize + normalize + QKV GEMM =================
    {
        if (tid < 16) {
            float s = 0.f, ss = 0.f;
#pragma unroll
            for (int j = 0; j < 16; ++j) { float2 p = part[tid * 16 + j]; s += p.x; ss += p.y; }
            float mu = s / 65536.f;
            float var = ss / 65536.f - mu * mu;
            sm.p2.mu[tid]   = mu;
            sm.p2.rstd[tid] = rsqrtf(var + 1e-5f);
        }
        __syncthreads();
        const int tok0 = bid * 16;
        {   // thread = channel c; 16 tokens
            const int c = tid;
            const float mu = sm.p2.mu[c >> 4], rs = sm.p2.rstd[c >> 4];
            const float g = gamma[c], bt = beta[c];
            const float4* xr = (const float4*)(x + c * N_TOK + tok0);
#pragma unroll
            for (int q4 = 0; q4 < 4; ++q4) {
                float4 v = xr[q4];
                sm.p2.xn[q4 * 4 + 0][c] = f2bf((v.x - mu) * rs * g + bt);
                sm.p2.xn[q4 * 4 + 1][c] = f2bf((v.y - mu) * rs * g + bt);
                sm.p2.xn[q4 * 4 + 2][c] = f2bf((v.z - mu) * rs * g + bt);
                sm.p2.xn[q4 * 4 + 3][c] = f2bf((v.w - mu) * rs * g + bt);
            }
        }
        __syncthreads();
        // wave = head; 12 m-tiles of 16 rows (0..3 Q, 4..7 K, 8..11 V)
        f32x4 acc[12];
#pragma unroll
        for (int mt = 0; mt < 12; ++mt) acc[mt] = f32x4{0, 0, 0, 0};
#pragma unroll
        for (int kc = 0; kc < 8; ++kc) {
            bf16x8 bfrag = *(const bf16x8*)(&sm.p2.xn[low][kc * 32 + quad * 8]);
#pragma unroll
            for (int mt = 0; mt < 12; ++mt) {
                bf16x8 afrag = *(const bf16x8*)(wq + (wave * 192 + mt * 16 + low) * 256 + kc * 32 + quad * 8);
                acc[mt] = __builtin_amdgcn_mfma_f32_16x16x32_bf16(afrag, bfrag, acc[mt], 0, 0, 0);
            }
        }
        const int tok = tok0 + low;
#pragma unroll
        for (int mt = 0; mt < 4; ++mt)
#pragma unroll
            for (int r = 0; r < 4; ++r)
                QT[(wave * N_TOK + tok) * 64 + mt * 16 + quad * 4 + r] = f2bf(acc[mt][r]);
#pragma unroll
        for (int mt = 0; mt < 4; ++mt)
#pragma unroll
            for (int r = 0; r < 4; ++r)
                KTm[(wave * N_TOK + tok) * 64 + mt * 16 + quad * 4 + r] = f2bf(acc[4 + mt][r]);
#pragma unroll
        for (int mt = 0; mt < 4; ++mt)
#pragma unroll
            for (int r = 0; r < 4; ++r)
                Vc[(wave * 64 + mt * 16 + quad * 4 + r) * N_TOK + tok] = f2bf(acc[8 + mt][r]);
    }
    gridbar(slots, 2);

    // ================= P3: attention (waves-over-keys, fixed-max exp2) =================
    {
        const int head = bid >> 6;
        const int qb   = (bid & 63) * 64;
        const u16* Qh = QT  + head * N_TOK * 64;
        const u16* Kh = KTm + head * N_TOK * 64;
        const u16* Vh = Vc  + head * 64 * N_TOK;
        u16* Pw = sm.ps[wave];

        bf16x8 ones;
#pragma unroll
        for (int i = 0; i < 8; ++i) ones[i] = (short)0x3F80;

        bf16x8 bq[4][2];
#pragma unroll
        for (int tn = 0; tn < 4; ++tn)
#pragma unroll
            for (int kh = 0; kh < 2; ++kh)
                bq[tn][kh] = *(const bf16x8*)(Qh + (qb + tn * 16 + low) * 64 + kh * 32 + quad * 8);

        f32x4 oa[4][4], lC[4];
#pragma unroll
        for (int tm = 0; tm < 4; ++tm) {
            lC[tm] = f32x4{0, 0, 0, 0};
#pragma unroll
            for (int cn = 0; cn < 4; ++cn) oa[tm][cn] = f32x4{0, 0, 0, 0};
        }

        auto load_frags = [&](Frags& F, int sbase) {
#pragma unroll
            for (int sq = 0; sq < 4; ++sq)
#pragma unroll
                for (int kh = 0; kh < 2; ++kh)
                    F.ak[sq][kh] = *(const bf16x8*)(Kh + (sbase + sq * 16 + low) * 64 + kh * 32 + quad * 8);
#pragma unroll
            for (int f = 0; f < 2; ++f)
#pragma unroll
                for (int cn = 0; cn < 4; ++cn)
                    F.bv[f][cn] = *(const bf16x8*)(Vh + (cn * 16 + low) * N_TOK + sbase + f * 32 + quad * 8);
        };

        auto compute_tile = [&](const Frags& F) {
            f32x4 sa[4][4];
#pragma unroll
            for (int sq = 0; sq < 4; ++sq)
#pragma unroll
                for (int tn = 0; tn < 4; ++tn) sa[sq][tn] = f32x4{0, 0, 0, 0};
#pragma unroll
            for (int kh = 0; kh < 2; ++kh)
#pragma unroll
                for (int sq = 0; sq < 4; ++sq)
#pragma unroll
                    for (int tn = 0; tn < 4; ++tn)
                        sa[sq][tn] = __builtin_amdgcn_mfma_f32_16x16x32_bf16(F.ak[sq][kh], bq[tn][kh], sa[sq][tn], 0, 0, 0);
#pragma unroll
            for (int sq = 0; sq < 4; ++sq)
#pragma unroll
                for (int tn = 0; tn < 4; ++tn) {
                    float p0 = __builtin_amdgcn_exp2f(sa[sq][tn][0]);
                    float p1 = __builtin_amdgcn_exp2f(sa[sq][tn][1]);
                    float p2 = __builtin_amdgcn_exp2f(sa[sq][tn][2]);
                    float p3 = __builtin_amdgcn_exp2f(sa[sq][tn][3]);
                    uint2 pk; pk.x = packtr(p0, p1); pk.y = packtr(p2, p3);
                    int u = (sq * 2 + (quad >> 1)) ^ low7;
                    *(uint2*)(Pw + (tn * 16 + low) * 64 + u * 8 + (quad & 1) * 4) = pk;
                }
            asm volatile("s_waitcnt lgkmcnt(0)" ::: "memory");  // wave-private round-trip
#pragma unroll
            for (int tm = 0; tm < 4; ++tm)
#pragma unroll
                for (int f = 0; f < 2; ++f) {
                    bf16x8 ap = *(const bf16x8*)(Pw + (tm * 16 + low) * 64 + (((f * 4 + quad) ^ low7) * 8));
                    lC[tm] = __builtin_amdgcn_mfma_f32_16x16x32_bf16(ap, ones, lC[tm], 0, 0, 0);
#pragma unroll
                    for (int cn = 0; cn < 4; ++cn)
                        oa[tm][cn] = __builtin_amdgcn_mfma_f32_16x16x32_bf16(ap, F.bv[f][cn], oa[tm][cn], 0, 0, 0);
                }
        };

        Frags Fa, Fb;
        load_frags(Fa, wave * 64);
#pragma unroll 1
        for (int i = 0; i < 16; i += 2) {
            load_frags(Fb, (wave + 4 * (i + 1)) * 64);
            compute_tile(Fa);
            if (i + 2 < 16) load_frags(Fa, (wave + 4 * (i + 2)) * 64);
            compute_tile(Fb);
        }

        // in-block combine across 4 waves
        __syncthreads();
        if ((wave & 1) == 0) {
            int bsel = wave >> 1;
#pragma unroll
            for (int tm = 0; tm < 4; ++tm)
#pragma unroll
                for (int r = 0; r < 4; ++r) {
                    int t = tm * 16 + quad * 4 + r;
                    if (low == 0) sm.cb.lb[bsel][t] = lC[tm][r];
#pragma unroll
                    for (int cn = 0; cn < 4; ++cn)
                        sm.cb.buf[bsel][t][cn * 16 + low] = oa[tm][cn][r];
                }
        }
        __syncthreads();
        if ((wave & 1) == 1) {
            int bsel = wave >> 1;
#pragma unroll
            for (int tm = 0; tm < 4; ++tm)
#pragma unroll
                for (int r = 0; r < 4; ++r) {
                    int t = tm * 16 + quad * 4 + r;
                    if (low == 0) sm.cb.lb[bsel][t] += lC[tm][r];
#pragma unroll
                    for (int cn = 0; cn < 4; ++cn)
                        sm.cb.buf[bsel][t][cn * 16 + low] += oa[tm][cn][r];
                }
        }
        __syncthreads();
        {
            int t = tid >> 2, c0 = (tid & 3) * 16;
            float li = 1.f / (sm.cb.lb[0][t] + sm.cb.lb[1][t]);
#pragma unroll
            for (int j = 0; j < 16; ++j) {
                int c = c0 + j;
                float o = (sm.cb.buf[0][t][c] + sm.cb.buf[1][t][c]) * li;
                hT[(qb + t) * C_CH + head * 64 + c] = f2bf(o);
            }
        }
    }
    gridbar(slots, 3);

    // ================= P4: proj GEMM + bias + residual =================
    {
        const int tok0 = bid * 16;
        f32x4 pacc[4];
#pragma unroll
        for (int mt = 0; mt < 4; ++mt) pacc[mt] = f32x4{0, 0, 0, 0};
#pragma unroll
        for (int kc = 0; kc < 8; ++kc) {
            bf16x8 bfrag = *(const bf16x8*)(hT + (tok0 + low) * C_CH + kc * 32 + quad * 8);
#pragma unroll
            for (int mt = 0; mt < 4; ++mt) {
                bf16x8 afrag = *(const bf16x8*)(wp + (wave * 64 + mt * 16 + low) * 256 + kc * 32 + quad * 8);
                pacc[mt] = __builtin_amdgcn_mfma_f32_16x16x32_bf16(afrag, bfrag, pacc[mt], 0, 0, 0);
            }
        }
        const int tok = tok0 + low;
#pragma unroll
        for (int mt = 0; mt < 4; ++mt)
#pragma unroll
            for (int r = 0; r < 4; ++r) {
                int o = wave * 64 + mt * 16 + quad * 4 + r;
                out[o * N_TOK + tok] = pacc[mt][r] + bproj[o] + x[o * N_TOK + tok];
            }
    }
}

extern "C" void kernel_launch(void* const* d_in, const int* in_sizes, int n_in,
                              void* d_out, int out_size, void* d_ws, size_t ws_size,
                              hipStream_t stream) {
    const float* x      = (const float*)d_in[0];
    const float* gamma  = (const float*)d_in[1];
    const float* beta   = (const float*)d_in[2];
    const float* w_qkv  = (const float*)d_in[3];
    const float* w_proj = (const float*)d_in[4];
    const float* b_proj = (const float*)d_in[5];
    float* out = (float*)d_out;

    char* base = (char*)d_ws;
    unsigned* slots = (unsigned*)base;                 // 1 KB (poisoned 0xAA each call — by design)
    float2*   part  = (float2*)(base + 1024);          // 2 KB
    u16*      wq    = (u16*)(base + 4096);             // 384 KB
    u16*      wp    = (u16*)(base + 397312);           // 128 KB
    u16*      QT    = (u16*)(base + 528384);           // 2 MB
    u16*      KTm   = (u16*)(base + 2625536);          // 2 MB
    u16*      Vc    = (u16*)(base + 4722688);          // 2 MB
    u16*      hT    = (u16*)(base + 6819840);          // 2 MB

    fused_attn_block<<<256, 256, 0, stream>>>(x, gamma, beta, w_qkv, w_proj, b_proj,
                                              slots, part, wq, wp, QT, KTm, Vc, hT, out);
}

// Round 8
// 202.456 us; speedup vs baseline: 1.3722x; 1.2004x over previous
//
#include <hip/hip_runtime.h>
#include <math.h>

// B=1, C=256, N=16^3=4096 tokens, 16 groups, 4 heads, d=64.
// Single persistent kernel: 256 blocks x 256 threads.
// R8 barrier: slot publish/poll via agent-scope atomic RMWs (executed at the
// coherent LLC - immediately visible cross-XCD, no buffer_inv storm), with one
// release fence before publish and one acquire fence after the spin.
#define N_TOK 4096
#define C_CH  256

typedef short bf16x8 __attribute__((ext_vector_type(8)));
typedef float f32x4  __attribute__((ext_vector_type(4)));
typedef unsigned short u16;

__device__ __forceinline__ u16 f2bf(float f) {
    union { float f; unsigned u; } v; v.f = f;
    unsigned r = v.u + 0x7FFF + ((v.u >> 16) & 1);   // RNE
    return (u16)(r >> 16);
}
// pack two floats to bf16 pair (truncation) in one v_perm_b32
__device__ __forceinline__ unsigned packtr(float a, float b) {
    union { float f; unsigned u; } ua, ub; ua.f = a; ub.f = b;
    return __builtin_amdgcn_perm(ub.u, ua.u, 0x07060302u);  // lo=hi16(a), hi=hi16(b)
}

// Grid barrier. Poison-proof: 0xAAAAAAAA reads negative as int, never satisfies
// >= phase; exchange-publish overwrites poison unconditionally; monotone phases
// make race-ahead safe. RMWs execute at the LLC (coherent across XCDs).
__device__ __forceinline__ void gridbar(unsigned* slots, unsigned phase) {
    __builtin_amdgcn_fence(__ATOMIC_RELEASE, "agent");   // flush this XCD's L2 to LLC
    __syncthreads();
    if (threadIdx.x == 0)
        __hip_atomic_exchange(&slots[blockIdx.x], phase,
                              __ATOMIC_RELAXED, __HIP_MEMORY_SCOPE_AGENT);
    if (threadIdx.x < 64) {
#pragma unroll 1
        for (int j = 0; j < 4; ++j) {
            while ((int)__hip_atomic_fetch_add(&slots[threadIdx.x * 4 + j], 0u,
                                               __ATOMIC_RELAXED, __HIP_MEMORY_SCOPE_AGENT)
                   < (int)phase) {
                __builtin_amdgcn_s_sleep(2);
            }
        }
    }
    __syncthreads();
    __builtin_amdgcn_fence(__ATOMIC_ACQUIRE, "agent");   // invalidate stale lines once
}

union SM {
    struct { float rs[4], rss[4]; } p1;
    struct { float mu[16], rstd[16]; u16 xn[16][264]; } p2;   // +8 pad
    u16 ps[4][4096];                                          // attn per-wave P (swizzled)
    struct { float buf[2][64][65]; float lb[2][64]; } cb;     // attn combine (33.8KB max)
};

struct Frags { bf16x8 ak[4][2]; bf16x8 bv[2][4]; };

__global__ __launch_bounds__(256, 1) void fused_attn_block(
        const float* __restrict__ x,
        const float* __restrict__ gamma,
        const float* __restrict__ beta,
        const float* __restrict__ wqkv,
        const float* __restrict__ wproj,
        const float* __restrict__ bproj,
        unsigned* __restrict__ slots,
        float2* __restrict__ part,
        u16* __restrict__ wq, u16* __restrict__ wp,
        u16* __restrict__ QT, u16* __restrict__ KTm, u16* __restrict__ Vc,
        u16* __restrict__ hT,
        float* __restrict__ out) {
    __shared__ SM sm;
    const int bid  = blockIdx.x;      // 0..255
    const int tid  = threadIdx.x;     // 0..255
    const int wave = tid >> 6, lane = tid & 63;
    const int quad = lane >> 4, low = lane & 15;
    const int low7 = low & 7;

    // ================= P1: weight cvt + GN partial sums (1 channel / block) ====
    {
        int i4 = (bid * 256 + tid) * 4;
        if (i4 < 196608) {
            float4 v = *(const float4*)(wqkv + i4);
            // Q rows pre-scaled by 0.125*log2(e) so softmax uses exp2 directly
            float s = (((i4 >> 8) % 192) < 64) ? 0.18033688f : 1.0f;
            u16 r[4] = { f2bf(v.x * s), f2bf(v.y * s), f2bf(v.z * s), f2bf(v.w * s) };
            *(uint2*)(wq + i4) = *(uint2*)r;
        } else {
            int j = i4 - 196608;
            float4 v = *(const float4*)(wproj + j);
            u16 r[4] = { f2bf(v.x), f2bf(v.y), f2bf(v.z), f2bf(v.w) };
            *(uint2*)(wp + j) = *(uint2*)r;
        }
        // GN partials: block bid covers channel bid (4096 floats = 1024 float4)
        const float4* xp = (const float4*)x + bid * 1024;
        float s = 0.f, ss = 0.f;
#pragma unroll
        for (int k = 0; k < 4; ++k) {
            float4 v = xp[tid + k * 256];
            s  += v.x + v.y + v.z + v.w;
            ss += v.x * v.x + v.y * v.y + v.z * v.z + v.w * v.w;
        }
#pragma unroll
        for (int off = 1; off < 64; off <<= 1) {
            s  += __shfl_xor(s, off, 64);
            ss += __shfl_xor(ss, off, 64);
        }
        if (lane == 0) { sm.p1.rs[wave] = s; sm.p1.rss[wave] = ss; }
        __syncthreads();
        if (tid == 0)
            part[bid] = make_float2(sm.p1.rs[0] + sm.p1.rs[1] + sm.p1.rs[2] + sm.p1.rs[3],
                                    sm.p1.rss[0] + sm.p1.rss[1] + sm.p1.rss[2] + sm.p1.rss[3]);
    }
    gridbar(slots, 1);

    // ================= P2: stats finalize + normalize + QKV GEMM =================
    {
        if (tid < 16) {
            float s = 0.f, ss = 0.f;
#pragma unroll
            for (int j = 0; j < 16; ++j) { float2 p = part[tid * 16 + j]; s += p.x; ss += p.y; }
            float mu = s / 65536.f;
            float var = ss / 65536.f - mu * mu;
            sm.p2.mu[tid]   = mu;
            sm.p2.rstd[tid] = rsqrtf(var + 1e-5f);
        }
        __syncthreads();
        const int tok0 = bid * 16;
        {   // thread = channel c; 16 tokens
            const int c = tid;
            const float mu = sm.p2.mu[c >> 4], rs = sm.p2.rstd[c >> 4];
            const float g = gamma[c], bt = beta[c];
            const float4* xr = (const float4*)(x + c * N_TOK + tok0);
#pragma unroll
            for (int q4 = 0; q4 < 4; ++q4) {
                float4 v = xr[q4];
                sm.p2.xn[q4 * 4 + 0][c] = f2bf((v.x - mu) * rs * g + bt);
                sm.p2.xn[q4 * 4 + 1][c] = f2bf((v.y - mu) * rs * g + bt);
                sm.p2.xn[q4 * 4 + 2][c] = f2bf((v.z - mu) * rs * g + bt);
                sm.p2.xn[q4 * 4 + 3][c] = f2bf((v.w - mu) * rs * g + bt);
            }
        }
        __syncthreads();
        // wave = head; 12 m-tiles of 16 rows (0..3 Q, 4..7 K, 8..11 V)
        f32x4 acc[12];
#pragma unroll
        for (int mt = 0; mt < 12; ++mt) acc[mt] = f32x4{0, 0, 0, 0};
#pragma unroll
        for (int kc = 0; kc < 8; ++kc) {
            bf16x8 bfrag = *(const bf16x8*)(&sm.p2.xn[low][kc * 32 + quad * 8]);
#pragma unroll
            for (int mt = 0; mt < 12; ++mt) {
                bf16x8 afrag = *(const bf16x8*)(wq + (wave * 192 + mt * 16 + low) * 256 + kc * 32 + quad * 8);
                acc[mt] = __builtin_amdgcn_mfma_f32_16x16x32_bf16(afrag, bfrag, acc[mt], 0, 0, 0);
            }
        }
        const int tok = tok0 + low;
#pragma unroll
        for (int mt = 0; mt < 4; ++mt)
#pragma unroll
            for (int r = 0; r < 4; ++r)
                QT[(wave * N_TOK + tok) * 64 + mt * 16 + quad * 4 + r] = f2bf(acc[mt][r]);
#pragma unroll
        for (int mt = 0; mt < 4; ++mt)
#pragma unroll
            for (int r = 0; r < 4; ++r)
                KTm[(wave * N_TOK + tok) * 64 + mt * 16 + quad * 4 + r] = f2bf(acc[4 + mt][r]);
#pragma unroll
        for (int mt = 0; mt < 4; ++mt)
#pragma unroll
            for (int r = 0; r < 4; ++r)
                Vc[(wave * 64 + mt * 16 + quad * 4 + r) * N_TOK + tok] = f2bf(acc[8 + mt][r]);
    }
    gridbar(slots, 2);

    // ================= P3: attention (waves-over-keys, fixed-max exp2) =================
    {
        const int head = bid >> 6;
        const int qb   = (bid & 63) * 64;
        const u16* Qh = QT  + head * N_TOK * 64;
        const u16* Kh = KTm + head * N_TOK * 64;
        const u16* Vh = Vc  + head * 64 * N_TOK;
        u16* Pw = sm.ps[wave];

        bf16x8 ones;
#pragma unroll
        for (int i = 0; i < 8; ++i) ones[i] = (short)0x3F80;

        bf16x8 bq[4][2];
#pragma unroll
        for (int tn = 0; tn < 4; ++tn)
#pragma unroll
            for (int kh = 0; kh < 2; ++kh)
                bq[tn][kh] = *(const bf16x8*)(Qh + (qb + tn * 16 + low) * 64 + kh * 32 + quad * 8);

        f32x4 oa[4][4], lC[4];
#pragma unroll
        for (int tm = 0; tm < 4; ++tm) {
            lC[tm] = f32x4{0, 0, 0, 0};
#pragma unroll
            for (int cn = 0; cn < 4; ++cn) oa[tm][cn] = f32x4{0, 0, 0, 0};
        }

        auto load_frags = [&](Frags& F, int sbase) {
#pragma unroll
            for (int sq = 0; sq < 4; ++sq)
#pragma unroll
                for (int kh = 0; kh < 2; ++kh)
                    F.ak[sq][kh] = *(const bf16x8*)(Kh + (sbase + sq * 16 + low) * 64 + kh * 32 + quad * 8);
#pragma unroll
            for (int f = 0; f < 2; ++f)
#pragma unroll
                for (int cn = 0; cn < 4; ++cn)
                    F.bv[f][cn] = *(const bf16x8*)(Vh + (cn * 16 + low) * N_TOK + sbase + f * 32 + quad * 8);
        };

        auto compute_tile = [&](const Frags& F) {
            f32x4 sa[4][4];
#pragma unroll
            for (int sq = 0; sq < 4; ++sq)
#pragma unroll
                for (int tn = 0; tn < 4; ++tn) sa[sq][tn] = f32x4{0, 0, 0, 0};
#pragma unroll
            for (int kh = 0; kh < 2; ++kh)
#pragma unroll
                for (int sq = 0; sq < 4; ++sq)
#pragma unroll
                    for (int tn = 0; tn < 4; ++tn)
                        sa[sq][tn] = __builtin_amdgcn_mfma_f32_16x16x32_bf16(F.ak[sq][kh], bq[tn][kh], sa[sq][tn], 0, 0, 0);
#pragma unroll
            for (int sq = 0; sq < 4; ++sq)
#pragma unroll
                for (int tn = 0; tn < 4; ++tn) {
                    float p0 = __builtin_amdgcn_exp2f(sa[sq][tn][0]);
                    float p1 = __builtin_amdgcn_exp2f(sa[sq][tn][1]);
                    float p2 = __builtin_amdgcn_exp2f(sa[sq][tn][2]);
                    float p3 = __builtin_amdgcn_exp2f(sa[sq][tn][3]);
                    uint2 pk; pk.x = packtr(p0, p1); pk.y = packtr(p2, p3);
                    int u = (sq * 2 + (quad >> 1)) ^ low7;
                    *(uint2*)(Pw + (tn * 16 + low) * 64 + u * 8 + (quad & 1) * 4) = pk;
                }
            asm volatile("s_waitcnt lgkmcnt(0)" ::: "memory");  // wave-private round-trip
#pragma unroll
            for (int tm = 0; tm < 4; ++tm)
#pragma unroll
                for (int f = 0; f < 2; ++f) {
                    bf16x8 ap = *(const bf16x8*)(Pw + (tm * 16 + low) * 64 + (((f * 4 + quad) ^ low7) * 8));
                    lC[tm] = __builtin_amdgcn_mfma_f32_16x16x32_bf16(ap, ones, lC[tm], 0, 0, 0);
#pragma unroll
                    for (int cn = 0; cn < 4; ++cn)
                        oa[tm][cn] = __builtin_amdgcn_mfma_f32_16x16x32_bf16(ap, F.bv[f][cn], oa[tm][cn], 0, 0, 0);
                }
        };

        Frags Fa, Fb;
        load_frags(Fa, wave * 64);
#pragma unroll 1
        for (int i = 0; i < 16; i += 2) {
            load_frags(Fb, (wave + 4 * (i + 1)) * 64);
            compute_tile(Fa);
            if (i + 2 < 16) load_frags(Fa, (wave + 4 * (i + 2)) * 64);
            compute_tile(Fb);
        }

        // in-block combine across 4 waves
        __syncthreads();
        if ((wave & 1) == 0) {
            int bsel = wave >> 1;
#pragma unroll
            for (int tm = 0; tm < 4; ++tm)
#pragma unroll
                for (int r = 0; r < 4; ++r) {
                    int t = tm * 16 + quad * 4 + r;
                    if (low == 0) sm.cb.lb[bsel][t] = lC[tm][r];
#pragma unroll
                    for (int cn = 0; cn < 4; ++cn)
                        sm.cb.buf[bsel][t][cn * 16 + low] = oa[tm][cn][r];
                }
        }
        __syncthreads();
        if ((wave & 1) == 1) {
            int bsel = wave >> 1;
#pragma unroll
            for (int tm = 0; tm < 4; ++tm)
#pragma unroll
                for (int r = 0; r < 4; ++r) {
                    int t = tm * 16 + quad * 4 + r;
                    if (low == 0) sm.cb.lb[bsel][t] += lC[tm][r];
#pragma unroll
                    for (int cn = 0; cn < 4; ++cn)
                        sm.cb.buf[bsel][t][cn * 16 + low] += oa[tm][cn][r];
                }
        }
        __syncthreads();
        {
            int t = tid >> 2, c0 = (tid & 3) * 16;
            float li = 1.f / (sm.cb.lb[0][t] + sm.cb.lb[1][t]);
#pragma unroll
            for (int j = 0; j < 16; ++j) {
                int c = c0 + j;
                float o = (sm.cb.buf[0][t][c] + sm.cb.buf[1][t][c]) * li;
                hT[(qb + t) * C_CH + head * 64 + c] = f2bf(o);
            }
        }
    }
    gridbar(slots, 3);

    // ================= P4: proj GEMM + bias + residual =================
    {
        const int tok0 = bid * 16;
        f32x4 pacc[4];
#pragma unroll
        for (int mt = 0; mt < 4; ++mt) pacc[mt] = f32x4{0, 0, 0, 0};
#pragma unroll
        for (int kc = 0; kc < 8; ++kc) {
            bf16x8 bfrag = *(const bf16x8*)(hT + (tok0 + low) * C_CH + kc * 32 + quad * 8);
#pragma unroll
            for (int mt = 0; mt < 4; ++mt) {
                bf16x8 afrag = *(const bf16x8*)(wp + (wave * 64 + mt * 16 + low) * 256 + kc * 32 + quad * 8);
                pacc[mt] = __builtin_amdgcn_mfma_f32_16x16x32_bf16(afrag, bfrag, pacc[mt], 0, 0, 0);
            }
        }
        const int tok = tok0 + low;
#pragma unroll
        for (int mt = 0; mt < 4; ++mt)
#pragma unroll
            for (int r = 0; r < 4; ++r) {
                int o = wave * 64 + mt * 16 + quad * 4 + r;
                out[o * N_TOK + tok] = pacc[mt][r] + bproj[o] + x[o * N_TOK + tok];
            }
    }
}

extern "C" void kernel_launch(void* const* d_in, const int* in_sizes, int n_in,
                              void* d_out, int out_size, void* d_ws, size_t ws_size,
                              hipStream_t stream) {
    const float* x      = (const float*)d_in[0];
    const float* gamma  = (const float*)d_in[1];
    const float* beta   = (const float*)d_in[2];
    const float* w_qkv  = (const float*)d_in[3];
    const float* w_proj = (const float*)d_in[4];
    const float* b_proj = (const float*)d_in[5];
    float* out = (float*)d_out;

    char* base = (char*)d_ws;
    unsigned* slots = (unsigned*)base;                 // 1 KB (poisoned 0xAA each call — by design)
    float2*   part  = (float2*)(base + 1024);          // 2 KB
    u16*      wq    = (u16*)(base + 4096);             // 384 KB
    u16*      wp    = (u16*)(base + 397312);           // 128 KB
    u16*      QT    = (u16*)(base + 528384);           // 2 MB
    u16*      KTm   = (u16*)(base + 2625536);          // 2 MB
    u16*      Vc    = (u16*)(base + 4722688);          // 2 MB
    u16*      hT    = (u16*)(base + 6819840);          // 2 MB

    fused_attn_block<<<256, 256, 0, stream>>>(x, gamma, beta, w_qkv, w_proj, b_proj,
                                              slots, part, wq, wp, QT, KTm, Vc, hT, out);
}